// Round 1
// baseline (1220.312 us; speedup 1.0000x reference)
//
#include <hip/hip_runtime.h>
#include <hip/hip_bf16.h>

#define BB 64
#define LL 800
#define DD 100
#define NFC 50
#define XPAD 101
#define LT 16
#define MT 64

// ---------------- embedding gather: xe[b,l,:] = emb[x[b,l],:] ----------------
__global__ __launch_bounds__(256) void k_gather(const int* __restrict__ x,
                                                const float* __restrict__ emb,
                                                float* __restrict__ xe) {
  int idx = blockIdx.x * 256 + threadIdx.x;
  const int total = BB * LL * (DD / 4);
  if (idx >= total) return;
  int d4 = idx % (DD / 4);
  int bl = idx / (DD / 4);
  int tok = x[bl];
  float4 v = reinterpret_cast<const float4*>(emb)[tok * (DD / 4) + d4];
  reinterpret_cast<float4*>(xe)[bl * (DD / 4) + d4] = v;
}

// ---------------- fused attention (flash-style, fp32) ----------------
// per block: one batch b, 16 consecutive l rows. Online softmax over m-tiles of 64.
// r[m] = ml*mm*(m!=l)*e[m] / (ml*S2 + Z*1e-13);  x_hat = sum r[m] xe[m] + xe[l]
__global__ __launch_bounds__(256) void k_attn(const float* __restrict__ xe,
                                              const int* __restrict__ mask,
                                              float* __restrict__ xh) {
  __shared__ float xl[LT * XPAD];
  __shared__ float xm[MT * XPAD];
  __shared__ float sc[LT * 68];
  __shared__ float ew[LT * MT];
  __shared__ float mk[MT];

  int blk = blockIdx.x;
  int b = blk / (LL / LT);
  int l0 = (blk % (LL / LT)) * LT;
  int t = threadIdx.x;
  const float* xb = xe + (size_t)b * LL * DD;

  for (int i = t; i < LT * DD; i += 256) {
    int r = i / DD, d = i - r * DD;
    xl[r * XPAD + d] = xb[(size_t)l0 * DD + i];
  }

  int li = t >> 4, q = t & 15;   // softmax / PV ownership: row li, lane q
  int lg = t >> 5, mg = t & 31;  // score ownership: rows {lg, lg+8}, cols {mg, mg+32}
  float acc[7];
#pragma unroll
  for (int j = 0; j < 7; ++j) acc[j] = 0.f;
  float M = -1e30f, Z = 0.f, S2 = 0.f;

  const int NTILE = (LL + MT - 1) / MT;  // 13
  for (int mt = 0; mt < NTILE; ++mt) {
    int m0 = mt * MT;
    __syncthreads();  // protect xm/ew reuse
    int nv = min(MT, LL - m0);
    for (int i = t; i < nv * DD; i += 256) {
      int r = i / DD, d = i - r * DD;
      xm[r * XPAD + d] = xb[(size_t)m0 * DD + i];
    }
    if (t < MT) mk[t] = (m0 + t < LL) ? (float)mask[b * LL + m0 + t] : 0.f;
    __syncthreads();

    // ---- scores: 2l x 2m register block, k=100 ----
    {
      int lA = lg, lB = lg + 8;
      int mA = mg, mB = mg + 32;
      float s00 = 0, s01 = 0, s10 = 0, s11 = 0;
      const float* pa0 = xl + lA * XPAD;
      const float* pa1 = xl + lB * XPAD;
      const float* pb0 = xm + mA * XPAD;
      const float* pb1 = xm + mB * XPAD;
      for (int k = 0; k < DD; ++k) {
        float a0 = pa0[k], a1 = pa1[k], b0 = pb0[k], b1 = pb1[k];
        s00 += a0 * b0; s01 += a0 * b1; s10 += a1 * b0; s11 += a1 * b1;
      }
      int gmA = m0 + mA, gmB = m0 + mB, glA = l0 + lA, glB = l0 + lB;
      if (gmA >= LL) { s00 = -1e30f; s10 = -1e30f; }
      if (gmB >= LL) { s01 = -1e30f; s11 = -1e30f; }
      if (gmA == glA) s00 = 0.f;  // diag zeroed BEFORE softmax
      if (gmB == glA) s01 = 0.f;
      if (gmA == glB) s10 = 0.f;
      if (gmB == glB) s11 = 0.f;
      sc[lA * 68 + mA] = s00; sc[lA * 68 + mB] = s01;
      sc[lB * 68 + mA] = s10; sc[lB * 68 + mB] = s11;
    }
    __syncthreads();

    // ---- online softmax update, row li handled by 16 lanes (4 m each) ----
    float scale;
    {
      int gl = l0 + li;
      float v0 = sc[li * 68 + q * 4 + 0];
      float v1 = sc[li * 68 + q * 4 + 1];
      float v2 = sc[li * 68 + q * 4 + 2];
      float v3 = sc[li * 68 + q * 4 + 3];
      float tmax = fmaxf(fmaxf(v0, v1), fmaxf(v2, v3));
      for (int o = 8; o >= 1; o >>= 1) tmax = fmaxf(tmax, __shfl_xor(tmax, o, 16));
      float newM = fmaxf(M, tmax);
      scale = __expf(M - newM);
      float e0 = __expf(v0 - newM);
      float e1 = __expf(v1 - newM);
      float e2 = __expf(v2 - newM);
      float e3 = __expf(v3 - newM);
      int mb = m0 + q * 4;
      float w0 = e0 * mk[q * 4 + 0] * (float)(mb + 0 != gl);
      float w1 = e1 * mk[q * 4 + 1] * (float)(mb + 1 != gl);
      float w2 = e2 * mk[q * 4 + 2] * (float)(mb + 2 != gl);
      float w3 = e3 * mk[q * 4 + 3] * (float)(mb + 3 != gl);
      float tz = (e0 + e1) + (e2 + e3);  // full softmax denom incl. diag term
      float ts = (w0 + w1) + (w2 + w3);  // masked, diag-excluded sum
      for (int o = 8; o >= 1; o >>= 1) {
        tz += __shfl_xor(tz, o, 16);
        ts += __shfl_xor(ts, o, 16);
      }
      Z = Z * scale + tz;
      S2 = S2 * scale + ts;
      M = newM;
      ew[li * MT + q * 4 + 0] = w0;
      ew[li * MT + q * 4 + 1] = w1;
      ew[li * MT + q * 4 + 2] = w2;
      ew[li * MT + q * 4 + 3] = w3;
    }
    __syncthreads();

    // ---- PV accumulate: thread owns (li, d = q + 16j) ----
    {
#pragma unroll
      for (int j = 0; j < 7; ++j) acc[j] *= scale;
      const float* ewr = ew + li * MT;
      for (int m = 0; m < MT; ++m) {
        float w = ewr[m];
        const float* xr = xm + m * XPAD + q;
#pragma unroll
        for (int j = 0; j < 6; ++j) acc[j] += w * xr[16 * j];
        if (q < 4) acc[6] += w * xr[96];
      }
    }
  }

  // ---- finalize ----
  {
    int gl = l0 + li;
    float ml = (float)mask[b * LL + gl];
    float denom = ml * S2 + Z * 1e-13f;
    float inv = ml / denom;
    float* xo = xh + ((size_t)b * LL + gl) * DD;
    const float* xlr = xl + li * XPAD;
#pragma unroll
    for (int j = 0; j < 6; ++j) {
      int d = q + 16 * j;
      xo[d] = acc[j] * inv + xlr[d];
    }
    if (q < 4) xo[q + 96] = acc[6] * inv + xlr[q + 96];
  }
}

// ---------------- conv branches: sliding GEMM + relu + global max ----------------
struct ConvP {
  const float* w[8];
  const float* bias[8];
};

__global__ __launch_bounds__(256) void k_conv(const float* __restrict__ xe,
                                              const float* __restrict__ xh,
                                              ConvP P, int* __restrict__ feat) {
  __shared__ float xt[68 * XPAD];
  __shared__ float wl[64 * XPAD];
  int bid = blockIdx.x;
  int ltile = bid % 13; int rest = bid / 13;
  int sz = rest & 3; rest >>= 2;
  int br = rest & 1; int b = rest >> 1;
  int s = (sz < 3) ? (sz + 1) : 5;
  int Lout = LL - s + 1;
  int l0 = ltile * 64;
  const float* inp = (br == 0 ? xe : xh) + (size_t)b * LL * DD;
  const float* wptr = P.w[br * 4 + sz];
  const float* bptr = P.bias[br * 4 + sz];
  int t = threadIdx.x;

  for (int i = t; i < 68 * DD; i += 256) {
    int r = i / DD, d = i - r * DD;
    int gl = l0 + r;
    xt[r * XPAD + d] = (gl < LL) ? inp[(size_t)gl * DD + d] : 0.f;
  }
  int nfg = t >> 4, lg = t & 15;
  float acc[4][4];
#pragma unroll
  for (int u = 0; u < 4; ++u)
#pragma unroll
    for (int v = 0; v < 4; ++v) acc[u][v] = 0.f;

  for (int i = 0; i < s; ++i) {
    __syncthreads();
    for (int j = t; j < 64 * DD; j += 256) {
      int nf = j / DD, d = j - nf * DD;
      wl[nf * XPAD + d] = (nf < NFC) ? wptr[(nf * s + i) * DD + d] : 0.f;
    }
    __syncthreads();
    for (int d = 0; d < DD; ++d) {
      float xv[4], wv[4];
#pragma unroll
      for (int u = 0; u < 4; ++u) xv[u] = xt[(lg + 16 * u + i) * XPAD + d];
#pragma unroll
      for (int v = 0; v < 4; ++v) wv[v] = wl[(nfg + 16 * v) * XPAD + d];
#pragma unroll
      for (int u = 0; u < 4; ++u)
#pragma unroll
        for (int v = 0; v < 4; ++v) acc[u][v] += xv[u] * wv[v];
    }
  }
#pragma unroll
  for (int v = 0; v < 4; ++v) {
    int nf = nfg + 16 * v;
    if (nf >= NFC) continue;
    float bv = bptr[nf];
    float mx = 0.f;  // relu floor; matches max-of-relu semantics
#pragma unroll
    for (int u = 0; u < 4; ++u) {
      int l = l0 + lg + 16 * u;
      if (l < Lout) {
        float cv = acc[u][v] + bv;
        cv = cv > 0.f ? cv : 0.f;
        mx = fmaxf(mx, cv);
      }
    }
    for (int o = 8; o >= 1; o >>= 1) mx = fmaxf(mx, __shfl_xor(mx, o, 16));
    if (lg == 0)
      atomicMax(&feat[((b * 2 + br) * 4 + sz) * NFC + nf], __float_as_int(mx));
  }
}

// ---------------- FC + branch sum ----------------
__global__ __launch_bounds__(256) void k_fc(const float* __restrict__ feat,
                                            const float* __restrict__ fw1,
                                            const float* __restrict__ fb1,
                                            const float* __restrict__ fw2,
                                            const float* __restrict__ fb2,
                                            float* __restrict__ out) {
  int id = blockIdx.x * 256 + threadIdx.x;
  if (id >= BB * NFC) return;
  int b = id / NFC, k = id - b * NFC;
  float a = fb1[k] + fb2[k];
  const float* f1 = feat + (size_t)(b * 2 + 0) * (4 * NFC);
  const float* f2 = feat + (size_t)(b * 2 + 1) * (4 * NFC);
  const float* w1 = fw1 + k * (4 * NFC);
  const float* w2 = fw2 + k * (4 * NFC);
  for (int j = 0; j < 4 * NFC; ++j) a += f1[j] * w1[j] + f2[j] * w2[j];
  out[id] = a;
}

extern "C" void kernel_launch(void* const* d_in, const int* in_sizes, int n_in,
                              void* d_out, int out_size, void* d_ws, size_t ws_size,
                              hipStream_t stream) {
  const int* x = (const int*)d_in[0];
  const int* mask = (const int*)d_in[2];
  const float* emb = (const float*)d_in[3];
  ConvP P;
  for (int br = 0; br < 2; ++br)
    for (int j = 0; j < 4; ++j) {
      P.w[br * 4 + j] = (const float*)d_in[4 + br * 10 + j * 2];
      P.bias[br * 4 + j] = (const float*)d_in[4 + br * 10 + j * 2 + 1];
    }
  const float* fw1 = (const float*)d_in[12];
  const float* fb1 = (const float*)d_in[13];
  const float* fw2 = (const float*)d_in[22];
  const float* fb2 = (const float*)d_in[23];

  float* xe = (float*)d_ws;
  float* xh = xe + (size_t)BB * LL * DD;
  int* feat = (int*)(xh + (size_t)BB * LL * DD);
  float* out = (float*)d_out;

  hipMemsetAsync(feat, 0, (size_t)BB * 2 * 4 * NFC * sizeof(int), stream);
  k_gather<<<(BB * LL * (DD / 4) + 255) / 256, 256, 0, stream>>>(x, emb, xe);
  k_attn<<<BB * (LL / LT), 256, 0, stream>>>(xe, mask, xh);
  k_conv<<<BB * 2 * 4 * 13, 256, 0, stream>>>(xe, xh, P, feat);
  k_fc<<<(BB * NFC + 255) / 256, 256, 0, stream>>>((const float*)feat, fw1, fb1,
                                                   fw2, fb2, out);
}

// Round 2
// 644.249 us; speedup vs baseline: 1.8942x; 1.8942x over previous
//
#include <hip/hip_runtime.h>
#include <hip/hip_bf16.h>

#define BB 64
#define LL 800
#define DD 100
#define NFC 50
#define XPAD 101
#define MPAD 832
#define DPAD 128

typedef __attribute__((ext_vector_type(8))) short short8;
typedef __attribute__((ext_vector_type(4))) float f32x4;
#define MFMA16(a, b, c) __builtin_amdgcn_mfma_f32_16x16x32_bf16(a, b, c, 0, 0, 0)

__device__ __forceinline__ ushort f2bf(float f) {
  unsigned u = __float_as_uint(f);
  u += 0x7fff + ((u >> 16) & 1);
  return (ushort)(u >> 16);
}

// ---- fused gather + bf16 prep: xe fp32, xeb[b][832][128] bf16, xeT[b][128][832] bf16
__global__ __launch_bounds__(256) void k_prep(const int* __restrict__ x,
                                              const float* __restrict__ emb,
                                              float* __restrict__ xe,
                                              short* __restrict__ xeb,
                                              short* __restrict__ xeT) {
  __shared__ float tile[64][129];
  __shared__ int toks[64];
  int b = blockIdx.x / 13, mt = blockIdx.x % 13;
  int m0 = mt * 64;
  int t = threadIdx.x;
  if (t < 64) toks[t] = (m0 + t < LL) ? x[b * LL + m0 + t] : 1;
  __syncthreads();
  for (int i = t; i < 64 * 128; i += 256) {
    int m = i >> 7, d = i & 127;
    int gm = m0 + m;
    float v = 0.f;
    if (gm < LL && d < DD) {
      v = emb[(size_t)toks[m] * DD + d];
      xe[((size_t)b * LL + gm) * DD + d] = v;
    }
    tile[m][d] = v;
    xeb[((size_t)b * MPAD + gm) * DPAD + d] = (short)f2bf(v);
  }
  __syncthreads();
  for (int i = t; i < 64 * 128; i += 256) {
    int m = i & 63, d = i >> 6;
    xeT[((size_t)b * DPAD + d) * MPAD + m0 + m] = (short)f2bf(tile[m][d]);
  }
}

// ---- MFMA attention: swapped scores, barrier-free flash loop (no max-sub) ----
__global__ __launch_bounds__(256) void k_attn(const short* __restrict__ xeb,
                                              const short* __restrict__ xeT,
                                              const float* __restrict__ xe,
                                              const int* __restrict__ mask,
                                              float* __restrict__ xh) {
  __shared__ float mkl[MPAD];
  __shared__ short Pl[4][512];  // per-wave P buffer [16 l][32 m] bf16, XOR-swizzled
  int b = blockIdx.x / 13, lt = blockIdx.x % 13, l0 = lt * 64;
  int t = threadIdx.x, w = t >> 6, lane = t & 63, g = lane >> 4, c = lane & 15;
  for (int i = t; i < MPAD; i += 256)
    mkl[i] = (i < LL) ? (float)mask[b * LL + i] : 0.f;
  __syncthreads();

  int lcol = l0 + 16 * w + c;  // this lane's l column
  const short* xrow = xeb + ((size_t)b * MPAD + lcol) * DPAD;
  short8 xlf[4];
#pragma unroll
  for (int ks = 0; ks < 4; ++ks)
    xlf[ks] = *reinterpret_cast<const short8*>(xrow + 32 * ks + 8 * g);

  f32x4 pv[7];
#pragma unroll
  for (int dt = 0; dt < 7; ++dt) pv[dt] = (f32x4){0.f, 0.f, 0.f, 0.f};
  float Z = 0.f, S2 = 0.f;
  char* Pb = (char*)Pl[w];
  const short* xebB = xeb + (size_t)b * MPAD * DPAD;
  const short* xTb = xeT + (size_t)b * DPAD * MPAD;

  for (int mc = 0; mc < 26; ++mc) {
    int m0 = mc * 32;
    f32x4 s0 = {0.f, 0.f, 0.f, 0.f}, s1 = {0.f, 0.f, 0.f, 0.f};
    const short* a0 = xebB + (size_t)(m0 + c) * DPAD + 8 * g;
#pragma unroll
    for (int ks = 0; ks < 4; ++ks) {
      short8 af0 = *reinterpret_cast<const short8*>(a0 + 32 * ks);
      short8 af1 = *reinterpret_cast<const short8*>(a0 + 16 * DPAD + 32 * ks);
      s0 = MFMA16(af0, xlf[ks], s0);
      s1 = MFMA16(af1, xlf[ks], s1);
    }
    float zc = 0.f, s2c = 0.f;
#pragma unroll
    for (int st = 0; st < 2; ++st) {
      f32x4 sv = st ? s1 : s0;
      ushort pk[4];
#pragma unroll
      for (int r = 0; r < 4; ++r) {
        int m = m0 + 16 * st + 4 * g + r;
        float e = 0.f;
        if (m < LL) e = (m == lcol) ? 1.0f : __expf(sv[r]);
        float wgt = (m == lcol) ? 0.f : e * mkl[m];
        zc += e;
        s2c += wgt;
        pk[r] = f2bf(wgt);
      }
      unsigned lo = (unsigned)pk[0] | ((unsigned)pk[1] << 16);
      unsigned hi = (unsigned)pk[2] | ((unsigned)pk[3] << 16);
      int addr = (c * 64 + 32 * st + 8 * g) ^ ((c & 3) << 4);
      *reinterpret_cast<uint2*>(Pb + addr) = make_uint2(lo, hi);
    }
    asm volatile("s_waitcnt lgkmcnt(0)" ::: "memory");
    __builtin_amdgcn_sched_barrier(0);
    short8 pa = *reinterpret_cast<const short8*>(Pb + ((c * 64 + 16 * g) ^ ((c & 3) << 4)));
    const short* bb = xTb + (size_t)c * MPAD + m0 + 8 * g;
#pragma unroll
    for (int dt = 0; dt < 7; ++dt) {
      short8 bf = *reinterpret_cast<const short8*>(bb + (size_t)dt * 16 * MPAD);
      pv[dt] = MFMA16(pa, bf, pv[dt]);
    }
    zc += __shfl_xor(zc, 16);
    zc += __shfl_xor(zc, 32);
    s2c += __shfl_xor(s2c, 16);
    s2c += __shfl_xor(s2c, 32);
    Z += zc;
    S2 += s2c;
  }

#pragma unroll
  for (int r = 0; r < 4; ++r) {
    int lrow = l0 + 16 * w + 4 * g + r;
    float Zr = __shfl(Z, 4 * g + r);
    float S2r = __shfl(S2, 4 * g + r);
    float mlr = mkl[lrow];
    float inv = mlr / (mlr * S2r + Zr * 1e-13f);
    if (lrow < LL) {
      const float* xer = xe + ((size_t)b * LL + lrow) * DD;
      float* xhr = xh + ((size_t)b * LL + lrow) * DD;
#pragma unroll
      for (int dt = 0; dt < 7; ++dt) {
        int d = 16 * dt + c;
        if (d < DD) xhr[d] = pv[dt][r] * inv + xer[d];
      }
    }
  }
}

// ---------------- conv branches: sliding GEMM + relu + global max ----------------
struct ConvP {
  const float* w[8];
  const float* bias[8];
};

__global__ __launch_bounds__(256) void k_conv(const float* __restrict__ xe,
                                              const float* __restrict__ xh,
                                              ConvP P, int* __restrict__ feat) {
  __shared__ float xt[68 * XPAD];
  __shared__ float wl[64 * XPAD];
  int bid = blockIdx.x;
  int ltile = bid % 13; int rest = bid / 13;
  int sz = rest & 3; rest >>= 2;
  int br = rest & 1; int b = rest >> 1;
  int s = (sz < 3) ? (sz + 1) : 5;
  int Lout = LL - s + 1;
  int l0 = ltile * 64;
  const float* inp = (br == 0 ? xe : xh) + (size_t)b * LL * DD;
  const float* wptr = P.w[br * 4 + sz];
  const float* bptr = P.bias[br * 4 + sz];
  int t = threadIdx.x;

  for (int i = t; i < 68 * DD; i += 256) {
    int r = i / DD, d = i - r * DD;
    int gl = l0 + r;
    xt[r * XPAD + d] = (gl < LL) ? inp[(size_t)gl * DD + d] : 0.f;
  }
  int nfg = t >> 4, lg = t & 15;
  float acc[4][4];
#pragma unroll
  for (int u = 0; u < 4; ++u)
#pragma unroll
    for (int v = 0; v < 4; ++v) acc[u][v] = 0.f;

  for (int i = 0; i < s; ++i) {
    __syncthreads();
    for (int j = t; j < 64 * DD; j += 256) {
      int nf = j / DD, d = j - nf * DD;
      wl[nf * XPAD + d] = (nf < NFC) ? wptr[(nf * s + i) * DD + d] : 0.f;
    }
    __syncthreads();
    for (int d = 0; d < DD; ++d) {
      float xv[4], wv[4];
#pragma unroll
      for (int u = 0; u < 4; ++u) xv[u] = xt[(lg + 16 * u + i) * XPAD + d];
#pragma unroll
      for (int v = 0; v < 4; ++v) wv[v] = wl[(nfg + 16 * v) * XPAD + d];
#pragma unroll
      for (int u = 0; u < 4; ++u)
#pragma unroll
        for (int v = 0; v < 4; ++v) acc[u][v] += xv[u] * wv[v];
    }
  }
#pragma unroll
  for (int v = 0; v < 4; ++v) {
    int nf = nfg + 16 * v;
    if (nf >= NFC) continue;
    float bv = bptr[nf];
    float mx = 0.f;
#pragma unroll
    for (int u = 0; u < 4; ++u) {
      int l = l0 + lg + 16 * u;
      if (l < Lout) {
        float cv = acc[u][v] + bv;
        cv = cv > 0.f ? cv : 0.f;
        mx = fmaxf(mx, cv);
      }
    }
    for (int o = 8; o >= 1; o >>= 1) mx = fmaxf(mx, __shfl_xor(mx, o, 16));
    if (lg == 0)
      atomicMax(&feat[((b * 2 + br) * 4 + sz) * NFC + nf], __float_as_int(mx));
  }
}

// ---------------- FC + branch sum ----------------
__global__ __launch_bounds__(256) void k_fc(const float* __restrict__ feat,
                                            const float* __restrict__ fw1,
                                            const float* __restrict__ fb1,
                                            const float* __restrict__ fw2,
                                            const float* __restrict__ fb2,
                                            float* __restrict__ out) {
  int id = blockIdx.x * 256 + threadIdx.x;
  if (id >= BB * NFC) return;
  int b = id / NFC, k = id - b * NFC;
  float a = fb1[k] + fb2[k];
  const float* f1 = feat + (size_t)(b * 2 + 0) * (4 * NFC);
  const float* f2 = feat + (size_t)(b * 2 + 1) * (4 * NFC);
  const float* w1 = fw1 + k * (4 * NFC);
  const float* w2 = fw2 + k * (4 * NFC);
  for (int j = 0; j < 4 * NFC; ++j) a += f1[j] * w1[j] + f2[j] * w2[j];
  out[id] = a;
}

extern "C" void kernel_launch(void* const* d_in, const int* in_sizes, int n_in,
                              void* d_out, int out_size, void* d_ws, size_t ws_size,
                              hipStream_t stream) {
  const int* x = (const int*)d_in[0];
  const int* mask = (const int*)d_in[2];
  const float* emb = (const float*)d_in[3];
  ConvP P;
  for (int br = 0; br < 2; ++br)
    for (int j = 0; j < 4; ++j) {
      P.w[br * 4 + j] = (const float*)d_in[4 + br * 10 + j * 2];
      P.bias[br * 4 + j] = (const float*)d_in[4 + br * 10 + j * 2 + 1];
    }
  const float* fw1 = (const float*)d_in[12];
  const float* fb1 = (const float*)d_in[13];
  const float* fw2 = (const float*)d_in[22];
  const float* fb2 = (const float*)d_in[23];

  char* base = (char*)d_ws;
  float* xe = (float*)base;                               // 20,480,000 B
  float* xh = (float*)(base + 20480000);                  // 20,480,000 B
  short* xeb = (short*)(base + 40960000);                 // 13,631,488 B
  short* xeT = (short*)(base + 54591488);                 // 13,631,488 B
  int* feat = (int*)(base + 68222976);                    // 102,400 B
  float* out = (float*)d_out;

  hipMemsetAsync(feat, 0, (size_t)BB * 2 * 4 * NFC * sizeof(int), stream);
  k_prep<<<BB * 13, 256, 0, stream>>>(x, emb, xe, xeb, xeT);
  k_attn<<<BB * 13, 256, 0, stream>>>(xeb, xeT, xe, mask, xh);
  k_conv<<<BB * 2 * 4 * 13, 256, 0, stream>>>(xe, xh, P, feat);
  k_fc<<<(BB * NFC + 255) / 256, 256, 0, stream>>>((const float*)feat, fw1, fb1,
                                                   fw2, fb2, out);
}

// Round 3
// 274.453 us; speedup vs baseline: 4.4463x; 2.3474x over previous
//
#include <hip/hip_runtime.h>
#include <hip/hip_bf16.h>

#define BB 64
#define LL 800
#define DD 100
#define NFC 50
#define MPAD 832
#define DPAD 128

typedef __attribute__((ext_vector_type(8))) short short8;
typedef __attribute__((ext_vector_type(4))) float f32x4;
#define MFMA16(a, b, c) __builtin_amdgcn_mfma_f32_16x16x32_bf16(a, b, c, 0, 0, 0)

struct ConvP {
  const float* w[8];
  const float* bias[8];
};

__device__ __forceinline__ ushort f2bf(float f) {
  unsigned u = __float_as_uint(f);
  u += 0x7fff + ((u >> 16) & 1);
  return (ushort)(u >> 16);
}

// ---- fused gather + bf16 prep: xe fp32, xeb[b][832][128] bf16, xeT[b][128][832] bf16
__global__ __launch_bounds__(256) void k_prep(const int* __restrict__ x,
                                              const float* __restrict__ emb,
                                              float* __restrict__ xe,
                                              short* __restrict__ xeb,
                                              short* __restrict__ xeT) {
  __shared__ float tile[64][129];
  __shared__ int toks[64];
  int b = blockIdx.x / 13, mt = blockIdx.x % 13;
  int m0 = mt * 64;
  int t = threadIdx.x;
  if (t < 64) toks[t] = (m0 + t < LL) ? x[b * LL + m0 + t] : 1;
  __syncthreads();
  for (int i = t; i < 64 * 128; i += 256) {
    int m = i >> 7, d = i & 127;
    int gm = m0 + m;
    float v = 0.f;
    if (gm < LL && d < DD) {
      v = emb[(size_t)toks[m] * DD + d];
      xe[((size_t)b * LL + gm) * DD + d] = v;
    }
    tile[m][d] = v;
    xeb[((size_t)b * MPAD + gm) * DPAD + d] = (short)f2bf(v);
  }
  __syncthreads();
  for (int i = t; i < 64 * 128; i += 256) {
    int m = i & 63, d = i >> 6;
    xeT[((size_t)b * DPAD + d) * MPAD + m0 + m] = (short)f2bf(tile[m][d]);
  }
}

// ---- bf16 weight pack: wb[br][sz][nf(64)][i(5)][d(128)] zero-padded ----
__global__ __launch_bounds__(256) void k_wprep(ConvP P, short* __restrict__ wb) {
  int idx = blockIdx.x * 256 + threadIdx.x;
  if (idx >= 2 * 4 * 64 * 5 * 128) return;
  int d = idx & 127;
  int r = idx >> 7;
  int i = r % 5; r /= 5;
  int nf = r & 63; r >>= 6;
  int sz = r & 3;
  int br = r >> 2;
  int s = (sz < 3) ? sz + 1 : 5;
  float v = 0.f;
  if (nf < NFC && i < s && d < DD) v = P.w[br * 4 + sz][(nf * s + i) * DD + d];
  wb[idx] = (short)f2bf(v);
}

// ---- MFMA attention: swapped scores, barrier-free flash loop (no max-sub) ----
__global__ __launch_bounds__(256) void k_attn(const short* __restrict__ xeb,
                                              const short* __restrict__ xeT,
                                              const float* __restrict__ xe,
                                              const int* __restrict__ mask,
                                              short* __restrict__ xhb) {
  __shared__ float mkl[MPAD];
  __shared__ short Pl[4][512];  // per-wave P buffer [16 l][32 m] bf16, XOR-swizzled
  int b = blockIdx.x / 13, lt = blockIdx.x % 13, l0 = lt * 64;
  int t = threadIdx.x, w = t >> 6, lane = t & 63, g = lane >> 4, c = lane & 15;
  for (int i = t; i < MPAD; i += 256)
    mkl[i] = (i < LL) ? (float)mask[b * LL + i] : 0.f;
  __syncthreads();

  int lcol = l0 + 16 * w + c;  // this lane's l column
  const short* xrow = xeb + ((size_t)b * MPAD + lcol) * DPAD;
  short8 xlf[4];
#pragma unroll
  for (int ks = 0; ks < 4; ++ks)
    xlf[ks] = *reinterpret_cast<const short8*>(xrow + 32 * ks + 8 * g);

  f32x4 pv[7];
#pragma unroll
  for (int dt = 0; dt < 7; ++dt) pv[dt] = (f32x4){0.f, 0.f, 0.f, 0.f};
  float Z = 0.f, S2 = 0.f;
  char* Pb = (char*)Pl[w];
  const short* xebB = xeb + (size_t)b * MPAD * DPAD;
  const short* xTb = xeT + (size_t)b * DPAD * MPAD;

  for (int mc = 0; mc < 26; ++mc) {
    int m0 = mc * 32;
    f32x4 s0 = {0.f, 0.f, 0.f, 0.f}, s1 = {0.f, 0.f, 0.f, 0.f};
    const short* a0 = xebB + (size_t)(m0 + c) * DPAD + 8 * g;
#pragma unroll
    for (int ks = 0; ks < 4; ++ks) {
      short8 af0 = *reinterpret_cast<const short8*>(a0 + 32 * ks);
      short8 af1 = *reinterpret_cast<const short8*>(a0 + 16 * DPAD + 32 * ks);
      s0 = MFMA16(af0, xlf[ks], s0);
      s1 = MFMA16(af1, xlf[ks], s1);
    }
    float zc = 0.f, s2c = 0.f;
#pragma unroll
    for (int st = 0; st < 2; ++st) {
      f32x4 sv = st ? s1 : s0;
      ushort pk[4];
#pragma unroll
      for (int r = 0; r < 4; ++r) {
        int m = m0 + 16 * st + 4 * g + r;
        float e = 0.f;
        if (m < LL) e = (m == lcol) ? 1.0f : __expf(sv[r]);
        float wgt = (m == lcol) ? 0.f : e * mkl[m];
        zc += e;
        s2c += wgt;
        pk[r] = f2bf(wgt);
      }
      unsigned lo = (unsigned)pk[0] | ((unsigned)pk[1] << 16);
      unsigned hi = (unsigned)pk[2] | ((unsigned)pk[3] << 16);
      int addr = (c * 64 + 32 * st + 8 * g) ^ ((c & 3) << 4);
      *reinterpret_cast<uint2*>(Pb + addr) = make_uint2(lo, hi);
    }
    asm volatile("s_waitcnt lgkmcnt(0)" ::: "memory");
    __builtin_amdgcn_sched_barrier(0);
    short8 pa = *reinterpret_cast<const short8*>(Pb + ((c * 64 + 16 * g) ^ ((c & 3) << 4)));
    const short* bb = xTb + (size_t)c * MPAD + m0 + 8 * g;
#pragma unroll
    for (int dt = 0; dt < 7; ++dt) {
      short8 bf = *reinterpret_cast<const short8*>(bb + (size_t)dt * 16 * MPAD);
      pv[dt] = MFMA16(pa, bf, pv[dt]);
    }
    zc += __shfl_xor(zc, 16);
    zc += __shfl_xor(zc, 32);
    s2c += __shfl_xor(s2c, 16);
    s2c += __shfl_xor(s2c, 32);
    Z += zc;
    S2 += s2c;
  }

#pragma unroll
  for (int r = 0; r < 4; ++r) {
    int lrow = l0 + 16 * w + 4 * g + r;
    float Zr = __shfl(Z, 4 * g + r);
    float S2r = __shfl(S2, 4 * g + r);
    short* xhr = xhb + ((size_t)b * MPAD + lrow) * DPAD;
    if (lrow < LL) {
      float mlr = mkl[lrow];
      float inv = mlr / (mlr * S2r + Zr * 1e-13f);
      const float* xer = xe + ((size_t)b * LL + lrow) * DD;
#pragma unroll
      for (int dt = 0; dt < 7; ++dt) {
        int d = 16 * dt + c;
        xhr[d] = (d < DD) ? (short)f2bf(pv[dt][r] * inv + xer[d]) : (short)0;
      }
      xhr[112 + c] = 0;
    } else {
#pragma unroll
      for (int dt = 0; dt < 8; ++dt) xhr[16 * dt + c] = 0;
    }
  }
}

// ---- conv as MFMA sliding GEMM: block = (b, br, 64-l tile), wave = 16-nf tile ----
template <int S>
__global__ __launch_bounds__(256) void k_convT(const short* __restrict__ xeb,
                                               const short* __restrict__ xhb,
                                               const short* __restrict__ wb,
                                               ConvP P, int* __restrict__ feat) {
  constexpr int sz = (S == 5) ? 3 : (S - 1);
  __shared__ short xt[68 * 128];
  int bid = blockIdx.x;
  int ltile = bid % 13;
  int rest = bid / 13;
  int br = rest & 1;
  int b = rest >> 1;
  int l0 = ltile * 64;
  const short* src = (br ? xhb : xeb) + (size_t)b * MPAD * DPAD;
  int t = threadIdx.x;

  // stage 68 rows x 128 cols bf16, XOR-swizzled 16B chunks (chunk ^= row&7)
  for (int i = t; i < 68 * 16; i += 256) {
    int row = i >> 4, c16 = i & 15;
    int gr = l0 + row;
    if (gr > MPAD - 1) gr = MPAD - 1;  // rows >=800 are zero
    short8 v = *reinterpret_cast<const short8*>(src + (size_t)gr * DPAD + c16 * 8);
    *reinterpret_cast<short8*>(&xt[row * 128 + ((c16 ^ (row & 7)) << 3)]) = v;
  }
  __syncthreads();

  int w = t >> 6, lane = t & 63, g = lane >> 4, c = lane & 15;
  // preload this wave's 16-nf weight fragments
  const short* wp = wb + ((size_t)(br * 4 + sz) * 64 + w * 16 + c) * 640 + 8 * g;
  short8 wf[S][4];
#pragma unroll
  for (int i2 = 0; i2 < S; ++i2)
#pragma unroll
    for (int ks = 0; ks < 4; ++ks)
      wf[i2][ks] = *reinterpret_cast<const short8*>(wp + i2 * 128 + 32 * ks);

  f32x4 acc[4];
#pragma unroll
  for (int u = 0; u < 4; ++u) acc[u] = (f32x4){0.f, 0.f, 0.f, 0.f};

#pragma unroll
  for (int lsub = 0; lsub < 4; ++lsub) {
#pragma unroll
    for (int i2 = 0; i2 < S; ++i2) {
      int row = lsub * 16 + c + i2;
      int rb = row * 128, rx = row & 7;
#pragma unroll
      for (int ks = 0; ks < 4; ++ks) {
        short8 af = *reinterpret_cast<const short8*>(&xt[rb + (((4 * ks + g) ^ rx) << 3)]);
        acc[lsub] = MFMA16(af, wf[i2][ks], acc[lsub]);
      }
    }
  }

  const int Lout = LL - S + 1;
  int nf = w * 16 + c;
  float bias = (nf < NFC) ? P.bias[br * 4 + sz][nf] : 0.f;
  float mx = 0.f;
#pragma unroll
  for (int lsub = 0; lsub < 4; ++lsub)
#pragma unroll
    for (int r = 0; r < 4; ++r) {
      int l = l0 + lsub * 16 + 4 * g + r;
      if (l < Lout) {
        float v = acc[lsub][r] + bias;
        mx = fmaxf(mx, v > 0.f ? v : 0.f);
      }
    }
  mx = fmaxf(mx, __shfl_xor(mx, 16));
  mx = fmaxf(mx, __shfl_xor(mx, 32));
  if (g == 0 && nf < NFC)
    atomicMax(&feat[((b * 2 + br) * 4 + sz) * NFC + nf], __float_as_int(mx));
}

// ---------------- FC + branch sum ----------------
__global__ __launch_bounds__(256) void k_fc(const float* __restrict__ feat,
                                            const float* __restrict__ fw1,
                                            const float* __restrict__ fb1,
                                            const float* __restrict__ fw2,
                                            const float* __restrict__ fb2,
                                            float* __restrict__ out) {
  int id = blockIdx.x * 256 + threadIdx.x;
  if (id >= BB * NFC) return;
  int b = id / NFC, k = id - b * NFC;
  float a = fb1[k] + fb2[k];
  const float* f1 = feat + (size_t)(b * 2 + 0) * (4 * NFC);
  const float* f2 = feat + (size_t)(b * 2 + 1) * (4 * NFC);
  const float* w1 = fw1 + k * (4 * NFC);
  const float* w2 = fw2 + k * (4 * NFC);
  for (int j = 0; j < 4 * NFC; ++j) a += f1[j] * w1[j] + f2[j] * w2[j];
  out[id] = a;
}

extern "C" void kernel_launch(void* const* d_in, const int* in_sizes, int n_in,
                              void* d_out, int out_size, void* d_ws, size_t ws_size,
                              hipStream_t stream) {
  const int* x = (const int*)d_in[0];
  const int* mask = (const int*)d_in[2];
  const float* emb = (const float*)d_in[3];
  ConvP P;
  for (int br = 0; br < 2; ++br)
    for (int j = 0; j < 4; ++j) {
      P.w[br * 4 + j] = (const float*)d_in[4 + br * 10 + j * 2];
      P.bias[br * 4 + j] = (const float*)d_in[4 + br * 10 + j * 2 + 1];
    }
  const float* fw1 = (const float*)d_in[12];
  const float* fb1 = (const float*)d_in[13];
  const float* fw2 = (const float*)d_in[22];
  const float* fb2 = (const float*)d_in[23];

  char* base = (char*)d_ws;
  float* xe = (float*)base;                     // 20,480,000 B
  short* xeb = (short*)(base + 20480000);       // 13,631,488 B
  short* xeT = (short*)(base + 34111488);       // 13,631,488 B
  short* xhb = (short*)(base + 47742976);       // 13,631,488 B
  short* wb = (short*)(base + 61374464);        //    655,360 B
  int* feat = (int*)(base + 62029824);          //    102,400 B
  float* out = (float*)d_out;

  hipMemsetAsync(feat, 0, (size_t)BB * 2 * 4 * NFC * sizeof(int), stream);
  k_prep<<<BB * 13, 256, 0, stream>>>(x, emb, xe, xeb, xeT);
  k_wprep<<<(2 * 4 * 64 * 5 * 128 + 255) / 256, 256, 0, stream>>>(P, wb);
  k_attn<<<BB * 13, 256, 0, stream>>>(xeb, xeT, xe, mask, xhb);
  k_convT<1><<<BB * 2 * 13, 256, 0, stream>>>(xeb, xhb, wb, P, feat);
  k_convT<2><<<BB * 2 * 13, 256, 0, stream>>>(xeb, xhb, wb, P, feat);
  k_convT<3><<<BB * 2 * 13, 256, 0, stream>>>(xeb, xhb, wb, P, feat);
  k_convT<5><<<BB * 2 * 13, 256, 0, stream>>>(xeb, xhb, wb, P, feat);
  k_fc<<<(BB * NFC + 255) / 256, 256, 0, stream>>>((const float*)feat, fw1, fb1,
                                                   fw2, fb2, out);
}

// Round 4
// 272.501 us; speedup vs baseline: 4.4782x; 1.0072x over previous
//
#include <hip/hip_runtime.h>
#include <hip/hip_bf16.h>

#define BB 64
#define LL 800
#define DD 100
#define NFC 50
#define MPAD 832
#define DPAD 128

typedef __attribute__((ext_vector_type(8))) short short8;
typedef __attribute__((ext_vector_type(4))) float f32x4;
#define MFMA16(a, b, c) __builtin_amdgcn_mfma_f32_16x16x32_bf16(a, b, c, 0, 0, 0)

struct ConvP {
  const float* w[8];
  const float* bias[8];
};

__device__ __forceinline__ ushort f2bf(float f) {
  unsigned u = __float_as_uint(f);
  u += 0x7fff + ((u >> 16) & 1);
  return (ushort)(u >> 16);
}
__device__ __forceinline__ float bf2f(short s) {
  return __uint_as_float(((unsigned)(ushort)s) << 16);
}

// ---- fused gather + bf16 prep: xeb[b][832][128], xeT[b][128][832] ----
__global__ __launch_bounds__(256) void k_prep(const int* __restrict__ x,
                                              const float* __restrict__ emb,
                                              short* __restrict__ xeb,
                                              short* __restrict__ xeT) {
  __shared__ float tile[64][129];
  __shared__ int toks[64];
  int bid = blockIdx.x;
  int xcd = bid & 7, slot = bid >> 3;        // same XCD mapping as k_attn
  int b = xcd + 8 * (slot / 13);
  int mt = slot % 13;
  int m0 = mt * 64;
  int t = threadIdx.x;
  if (t < 64) toks[t] = (m0 + t < LL) ? x[b * LL + m0 + t] : 1;
  __syncthreads();
  for (int i = t; i < 64 * 128; i += 256) {
    int m = i >> 7, d = i & 127;
    int gm = m0 + m;
    float v = 0.f;
    if (gm < LL && d < DD) v = emb[(size_t)toks[m] * DD + d];
    tile[m][d] = v;
    xeb[((size_t)b * MPAD + gm) * DPAD + d] = (short)f2bf(v);
  }
  __syncthreads();
  for (int i = t; i < 64 * 128; i += 256) {
    int m = i & 63, d = i >> 6;
    xeT[((size_t)b * DPAD + d) * MPAD + m0 + m] = (short)f2bf(tile[m][d]);
  }
}

// ---- bf16 weight pack: wb[br][sz][nf(64)][i(5)][d(128)] zero-padded ----
__global__ __launch_bounds__(256) void k_wprep(ConvP P, short* __restrict__ wb) {
  int idx = blockIdx.x * 256 + threadIdx.x;
  if (idx >= 2 * 4 * 64 * 5 * 128) return;
  int d = idx & 127;
  int r = idx >> 7;
  int i = r % 5; r /= 5;
  int nf = r & 63; r >>= 6;
  int sz = r & 3;
  int br = r >> 2;
  int s = (sz < 3) ? sz + 1 : 5;
  float v = 0.f;
  if (nf < NFC && i < s && d < DD) v = P.w[br * 4 + sz][(nf * s + i) * DD + d];
  wb[idx] = (short)f2bf(v);
}

// ---- MFMA attention: swapped scores, pipelined flash loop, XCD-local L2 ----
__global__ __launch_bounds__(256, 2) void k_attn(const short* __restrict__ xeb,
                                                 const short* __restrict__ xeT,
                                                 const int* __restrict__ mask,
                                                 short* __restrict__ xhb) {
  __shared__ float mkl[MPAD];
  __shared__ short Pl[4][640];  // per-wave [16 l rows][80B stride]: st*32 + g*8
  int bid = blockIdx.x;
  int xcd = bid & 7, slot = bid >> 3;  // batch b -> XCD b%8: panels stay L2-local
  int b = xcd + 8 * (slot / 13);
  int lt = slot % 13;
  int l0 = lt * 64;
  int t = threadIdx.x, w = t >> 6, lane = t & 63, g = lane >> 4, c = lane & 15;
  for (int i = t; i < MPAD; i += 256)
    mkl[i] = (i < LL) ? (float)mask[b * LL + i] : 0.f;
  __syncthreads();

  int lcol = l0 + 16 * w + c;  // this lane's l column
  const short* xebB = xeb + (size_t)b * MPAD * DPAD;
  const short* xTb = xeT + (size_t)b * DPAD * MPAD;
  const short* xrow = xebB + (size_t)lcol * DPAD;
  short8 xlf[4];
#pragma unroll
  for (int ks = 0; ks < 4; ++ks)
    xlf[ks] = *reinterpret_cast<const short8*>(xrow + 32 * ks + 8 * g);

  f32x4 pv[7];
#pragma unroll
  for (int dt = 0; dt < 7; ++dt) pv[dt] = (f32x4){0.f, 0.f, 0.f, 0.f};
  float Z = 0.f, S2 = 0.f;
  char* Pb = (char*)Pl[w];

  // preload A-frags for mc=0
  short8 curA[8], nextA[8];
  {
    const short* a0 = xebB + (size_t)c * DPAD + 8 * g;
#pragma unroll
    for (int ks = 0; ks < 4; ++ks) {
      curA[ks] = *reinterpret_cast<const short8*>(a0 + 32 * ks);
      curA[4 + ks] = *reinterpret_cast<const short8*>(a0 + 16 * DPAD + 32 * ks);
    }
  }

  for (int mc = 0; mc < 26; ++mc) {
    int m0 = mc * 32;
    // issue B-frag loads for THIS iter (consumed after the fence)
    short8 bf[7];
    const short* bb = xTb + (size_t)c * MPAD + m0 + 8 * g;
#pragma unroll
    for (int dt = 0; dt < 7; ++dt)
      bf[dt] = *reinterpret_cast<const short8*>(bb + (size_t)dt * 16 * MPAD);

    // scores on preloaded A
    f32x4 s0 = {0.f, 0.f, 0.f, 0.f}, s1 = {0.f, 0.f, 0.f, 0.f};
#pragma unroll
    for (int ks = 0; ks < 4; ++ks) {
      s0 = MFMA16(curA[ks], xlf[ks], s0);
      s1 = MFMA16(curA[4 + ks], xlf[ks], s1);
    }

    // issue A-frag loads for NEXT iter (latency hidden under exp+fence+PV)
    {
      int m0n = (mc < 25) ? m0 + 32 : 0;
      const short* a0 = xebB + (size_t)(m0n + c) * DPAD + 8 * g;
#pragma unroll
      for (int ks = 0; ks < 4; ++ks) {
        nextA[ks] = *reinterpret_cast<const short8*>(a0 + 32 * ks);
        nextA[4 + ks] = *reinterpret_cast<const short8*>(a0 + 16 * DPAD + 32 * ks);
      }
    }

    // softmax (no max-sub; scores O(1)); accumulate Z/S2 per-lane, reduce later
    ushort pk0[4], pk1[4];
#pragma unroll
    for (int r = 0; r < 4; ++r) {
      int m = m0 + 4 * g + r;
      float e0 = (m < LL) ? ((m == lcol) ? 1.0f : __expf(s0[r])) : 0.f;
      float w0 = (m == lcol) ? 0.f : e0 * mkl[m];
      Z += e0; S2 += w0; pk0[r] = f2bf(w0);
      int m1 = m + 16;
      float e1 = (m1 < LL) ? ((m1 == lcol) ? 1.0f : __expf(s1[r])) : 0.f;
      float w1 = (m1 == lcol) ? 0.f : e1 * mkl[m1];
      Z += e1; S2 += w1; pk1[r] = f2bf(w1);
    }
    *reinterpret_cast<uint2*>(Pb + c * 80 + g * 8) =
        make_uint2((unsigned)pk0[0] | ((unsigned)pk0[1] << 16),
                   (unsigned)pk0[2] | ((unsigned)pk0[3] << 16));
    *reinterpret_cast<uint2*>(Pb + c * 80 + 32 + g * 8) =
        make_uint2((unsigned)pk1[0] | ((unsigned)pk1[1] << 16),
                   (unsigned)pk1[2] | ((unsigned)pk1[3] << 16));
    asm volatile("s_waitcnt lgkmcnt(0)" ::: "memory");
    __builtin_amdgcn_sched_barrier(0);
    short8 pa = *reinterpret_cast<const short8*>(Pb + c * 80 + g * 16);

    // PV on prefetched B
#pragma unroll
    for (int dt = 0; dt < 7; ++dt) pv[dt] = MFMA16(pa, bf[dt], pv[dt]);

#pragma unroll
    for (int j = 0; j < 8; ++j) curA[j] = nextA[j];
  }
  Z += __shfl_xor(Z, 16);
  Z += __shfl_xor(Z, 32);
  S2 += __shfl_xor(S2, 16);
  S2 += __shfl_xor(S2, 32);

#pragma unroll
  for (int r = 0; r < 4; ++r) {
    int lrow = l0 + 16 * w + 4 * g + r;
    float Zr = __shfl(Z, 4 * g + r);
    float S2r = __shfl(S2, 4 * g + r);
    short* xhr = xhb + ((size_t)b * MPAD + lrow) * DPAD;
    if (lrow < LL) {
      float mlr = mkl[lrow];
      float inv = mlr / (mlr * S2r + Zr * 1e-13f);
      const short* xer = xebB + (size_t)lrow * DPAD;
#pragma unroll
      for (int dt = 0; dt < 7; ++dt) {
        int d = 16 * dt + c;
        xhr[d] = (d < DD) ? (short)f2bf(pv[dt][r] * inv + bf2f(xer[d])) : (short)0;
      }
      xhr[112 + c] = 0;
    } else {
#pragma unroll
      for (int dt = 0; dt < 8; ++dt) xhr[16 * dt + c] = 0;
    }
  }
}

// ---- conv as MFMA sliding GEMM: block = (b, br, 64-l tile), wave = 16-nf tile ----
template <int S>
__global__ __launch_bounds__(256) void k_convT(const short* __restrict__ xeb,
                                               const short* __restrict__ xhb,
                                               const short* __restrict__ wb,
                                               ConvP P, int* __restrict__ feat) {
  constexpr int sz = (S == 5) ? 3 : (S - 1);
  __shared__ short xt[68 * 128];
  int bid = blockIdx.x;
  int xcd = bid & 7, slot = bid >> 3;  // same batch->XCD map as attn
  int b = xcd + 8 * (slot / 26);
  int rem = slot % 26;
  int br = rem >= 13;
  int ltile = rem % 13;
  int l0 = ltile * 64;
  const short* src = (br ? xhb : xeb) + (size_t)b * MPAD * DPAD;
  int t = threadIdx.x;

  // stage 68 rows x 128 cols bf16, XOR-swizzled 16B chunks (chunk ^= row&7)
  for (int i = t; i < 68 * 16; i += 256) {
    int row = i >> 4, c16 = i & 15;
    int gr = l0 + row;
    if (gr > MPAD - 1) gr = MPAD - 1;  // rows >=800 are zero
    short8 v = *reinterpret_cast<const short8*>(src + (size_t)gr * DPAD + c16 * 8);
    *reinterpret_cast<short8*>(&xt[row * 128 + ((c16 ^ (row & 7)) << 3)]) = v;
  }
  __syncthreads();

  int w = t >> 6, lane = t & 63, g = lane >> 4, c = lane & 15;
  const short* wp = wb + ((size_t)(br * 4 + sz) * 64 + w * 16 + c) * 640 + 8 * g;
  short8 wf[S][4];
#pragma unroll
  for (int i2 = 0; i2 < S; ++i2)
#pragma unroll
    for (int ks = 0; ks < 4; ++ks)
      wf[i2][ks] = *reinterpret_cast<const short8*>(wp + i2 * 128 + 32 * ks);

  f32x4 acc[4];
#pragma unroll
  for (int u = 0; u < 4; ++u) acc[u] = (f32x4){0.f, 0.f, 0.f, 0.f};

#pragma unroll
  for (int lsub = 0; lsub < 4; ++lsub) {
#pragma unroll
    for (int i2 = 0; i2 < S; ++i2) {
      int row = lsub * 16 + c + i2;
      int rb = row * 128, rx = row & 7;
#pragma unroll
      for (int ks = 0; ks < 4; ++ks) {
        short8 af = *reinterpret_cast<const short8*>(&xt[rb + (((4 * ks + g) ^ rx) << 3)]);
        acc[lsub] = MFMA16(af, wf[i2][ks], acc[lsub]);
      }
    }
  }

  const int Lout = LL - S + 1;
  int nf = w * 16 + c;
  float bias = (nf < NFC) ? P.bias[br * 4 + sz][nf] : 0.f;
  float mx = 0.f;
#pragma unroll
  for (int lsub = 0; lsub < 4; ++lsub)
#pragma unroll
    for (int r = 0; r < 4; ++r) {
      int l = l0 + lsub * 16 + 4 * g + r;
      if (l < Lout) {
        float v = acc[lsub][r] + bias;
        mx = fmaxf(mx, v > 0.f ? v : 0.f);
      }
    }
  mx = fmaxf(mx, __shfl_xor(mx, 16));
  mx = fmaxf(mx, __shfl_xor(mx, 32));
  if (g == 0 && nf < NFC)
    atomicMax(&feat[((b * 2 + br) * 4 + sz) * NFC + nf], __float_as_int(mx));
}

// ---------------- FC + branch sum ----------------
__global__ __launch_bounds__(256) void k_fc(const float* __restrict__ feat,
                                            const float* __restrict__ fw1,
                                            const float* __restrict__ fb1,
                                            const float* __restrict__ fw2,
                                            const float* __restrict__ fb2,
                                            float* __restrict__ out) {
  int id = blockIdx.x * 256 + threadIdx.x;
  if (id >= BB * NFC) return;
  int b = id / NFC, k = id - b * NFC;
  float a = fb1[k] + fb2[k];
  const float* f1 = feat + (size_t)(b * 2 + 0) * (4 * NFC);
  const float* f2 = feat + (size_t)(b * 2 + 1) * (4 * NFC);
  const float* w1 = fw1 + k * (4 * NFC);
  const float* w2 = fw2 + k * (4 * NFC);
  for (int j = 0; j < 4 * NFC; ++j) a += f1[j] * w1[j] + f2[j] * w2[j];
  out[id] = a;
}

extern "C" void kernel_launch(void* const* d_in, const int* in_sizes, int n_in,
                              void* d_out, int out_size, void* d_ws, size_t ws_size,
                              hipStream_t stream) {
  const int* x = (const int*)d_in[0];
  const int* mask = (const int*)d_in[2];
  const float* emb = (const float*)d_in[3];
  ConvP P;
  for (int br = 0; br < 2; ++br)
    for (int j = 0; j < 4; ++j) {
      P.w[br * 4 + j] = (const float*)d_in[4 + br * 10 + j * 2];
      P.bias[br * 4 + j] = (const float*)d_in[4 + br * 10 + j * 2 + 1];
    }
  const float* fw1 = (const float*)d_in[12];
  const float* fb1 = (const float*)d_in[13];
  const float* fw2 = (const float*)d_in[22];
  const float* fb2 = (const float*)d_in[23];

  char* base = (char*)d_ws;
  short* xeb = (short*)base;                    // 13,631,488 B
  short* xeT = (short*)(base + 13631488);       // 13,631,488 B
  short* xhb = (short*)(base + 27262976);       // 13,631,488 B
  short* wb = (short*)(base + 40894464);        //    655,360 B
  int* feat = (int*)(base + 41549824);          //    102,400 B
  float* out = (float*)d_out;

  hipMemsetAsync(feat, 0, (size_t)BB * 2 * 4 * NFC * sizeof(int), stream);
  k_prep<<<BB * 13, 256, 0, stream>>>(x, emb, xeb, xeT);
  k_wprep<<<(2 * 4 * 64 * 5 * 128 + 255) / 256, 256, 0, stream>>>(P, wb);
  k_attn<<<BB * 13, 256, 0, stream>>>(xeb, xeT, mask, xhb);
  k_convT<1><<<BB * 2 * 13, 256, 0, stream>>>(xeb, xhb, wb, P, feat);
  k_convT<2><<<BB * 2 * 13, 256, 0, stream>>>(xeb, xhb, wb, P, feat);
  k_convT<3><<<BB * 2 * 13, 256, 0, stream>>>(xeb, xhb, wb, P, feat);
  k_convT<5><<<BB * 2 * 13, 256, 0, stream>>>(xeb, xhb, wb, P, feat);
  k_fc<<<(BB * NFC + 255) / 256, 256, 0, stream>>>((const float*)feat, fw1, fb1,
                                                   fw2, fb2, out);
}